// Round 7
// baseline (242.310 us; speedup 1.0000x reference)
//
#include <hip/hip_runtime.h>
#include <hip/hip_bf16.h>
#include <float.h>

// N=1024, M=1024, D=512, fp32 in/out.
// tanh(q+k) = 1 - 2/(1+exp2(CS*(q+k))), CS=2*log2(e), exp2 factorized:
// eq[n][d]=min(exp2(CS*qp),2^13)*c (c=2^-13 pre-scaled in proj),
// ekT[d][m]=min(exp2(CS*kp),2^13)^T.
// s[n,m] = -2*sum_d Ww[d]/(1+eq*ek) (row-const dropped; softmax shift-inv).
// R19: 8-term rational merge (1 rcp per 8 d via 3-level tree, c^8 scaling).
// R20-R25 lessons: score VALU floor ~35us (conserved across 4 structures);
// barrier-free reg-prefetch streaming (R25) is the best engine. The REAL
// unknown is the residue: total - score == 121 +/- 2 us for 6 rounds
// (proj+combine+ctx+launch, each individually <56us, invisible in top-5).
// R26: FUSE combine INTO score. Score re-tiled 4n x 128m x FULL 512d
// (grid (8,256)=2048 blocks=8/CU, same engine, same per-thread op count).
// Epilogue: mask+exp2+bf16 hi/lo split+Ph/Pl store+shfl rowsum->atomic rsum.
// DELETES: combine kernel, S buffer (33MB atomics + 4MB zero + 8MB re-read).
// 3 kernels total. Ph/Pl moved to old S region (score reads eq/ekT live).
// ws: eq 2MB | ekT 2MB | vph/vpl 2MB | Ph/Pl 4MB | rsum 4KB.

#define NROWS 1024
#define DDIM  512
#define MDIM  1024

typedef __attribute__((ext_vector_type(8))) short s8v;    // 8 bf16, 4 VGPR
typedef __attribute__((ext_vector_type(4))) float f4v;
typedef __attribute__((ext_vector_type(2))) float v2f;

__device__ __forceinline__ float bf2f(ushort h) {
    return __uint_as_float(((unsigned)h) << 16);
}
__device__ __forceinline__ ushort2 f2bf2(float a, float b) {   // packed cvt
    __hip_bfloat162 t = __float22bfloat162_rn(float2{a, b});
    union { __hip_bfloat162 v; ushort2 u; } c; c.v = t;
    return c.u;
}
__device__ __forceinline__ void hl2(float a, float b, ushort2& h, ushort2& l) {
    h = f2bf2(a, b);
    l = f2bf2(a - bf2f(h.x), b - bf2f(h.y));
}

// ---------------- K1: fused projection GEMMs (MFMA bf16 hi/lo, A^T-B) --------
// z=0: eq[n][d]:  A=q,  B=Wq, bias col, exp2+clamp, *c. Block (0,0,0) zeroes rsum.
// z=1: ekT[d][m]: A=Wk, B=kk, bias row, exp2+clamp.
// z=2: vpT[d][m]: A=Wv, B=v,  bias row, bf16 h/l out.
__global__ __launch_bounds__(256) void proj_gemm(
    const float* __restrict__ q, const float* __restrict__ kk_,
    const float* __restrict__ v,
    const float* __restrict__ Wq, const float* __restrict__ bq,
    const float* __restrict__ Wk, const float* __restrict__ bk,
    const float* __restrict__ Wv, const float* __restrict__ bv,
    float* __restrict__ eq, float* __restrict__ ekT,
    ushort* __restrict__ vph, ushort* __restrict__ vpl,
    float* __restrict__ rsum, float CS)
{
    __shared__ ushort Ah[4096], Al[4096], Bh[4096], Bl[4096];   // 32 KB

    const float* A; const float* B; const float* bias;
    int biasRow;
    if (blockIdx.z == 0)      { A = q;   B = Wq;  bias = bq; biasRow = 0; }
    else if (blockIdx.z == 1) { A = Wk;  B = kk_; bias = bk; biasRow = 1; }
    else                      { A = Wv;  B = v;   bias = bv; biasRow = 1; }

    const int bi = (blockIdx.z == 0) ? blockIdx.x : blockIdx.y;
    const int bj = (blockIdx.z == 0) ? blockIdx.y : blockIdx.x;

    const int t    = threadIdx.x;
    const int lane = t & 63;
    const int w    = t >> 6;
    const int lm   = lane & 15;
    const int lq   = lane >> 4;
    const int i0   = bi * 64;
    const int j0   = bj * 64;
    const int mh   = (w >> 1) * 32;
    const int nh   = (w & 1) * 32;

    // zero rsum (1024 floats) for score's atomics
    if (blockIdx.z == 0 && blockIdx.x == 0 && blockIdx.y == 0) {
        float4 zz = {0.f, 0.f, 0.f, 0.f};
        *(float4*)&rsum[t * 4] = zz;
    }

    f4v acc[2][2] = {{{0.f,0.f,0.f,0.f},{0.f,0.f,0.f,0.f}},
                     {{0.f,0.f,0.f,0.f},{0.f,0.f,0.f,0.f}}};
    float4 pa[4], pb[4];

    const int sr = t >> 4, sc4 = t & 15;
#pragma unroll
    for (int p = 0; p < 4; ++p) {
        int r = sr + p * 16;
        pa[p] = *(const float4*)&A[(size_t)(i0 + r) * DDIM + sc4 * 4];
        pb[p] = *(const float4*)&B[(size_t)(j0 + r) * DDIM + sc4 * 4];
    }

    for (int kc = 0; kc < 8; ++kc) {
        __syncthreads();
#pragma unroll
        for (int p = 0; p < 4; ++p) {
            int r = sr + p * 16;
            int ad = r * 64 + (((sc4 >> 1) ^ (r & 7)) << 3) + (sc4 & 1) * 4;
            ushort2 h01, l01, h23, l23;
            hl2(pa[p].x, pa[p].y, h01, l01);
            hl2(pa[p].z, pa[p].w, h23, l23);
            ushort4 ha = {h01.x, h01.y, h23.x, h23.y};
            ushort4 la = {l01.x, l01.y, l23.x, l23.y};
            *(ushort4*)&Ah[ad] = ha;
            *(ushort4*)&Al[ad] = la;
            hl2(pb[p].x, pb[p].y, h01, l01);
            hl2(pb[p].z, pb[p].w, h23, l23);
            ushort4 hb = {h01.x, h01.y, h23.x, h23.y};
            ushort4 lb = {l01.x, l01.y, l23.x, l23.y};
            *(ushort4*)&Bh[ad] = hb;
            *(ushort4*)&Bl[ad] = lb;
        }
        __syncthreads();
        if (kc < 7) {
            const int k0 = (kc + 1) * 64;
#pragma unroll
            for (int p = 0; p < 4; ++p) {
                int r = sr + p * 16;
                pa[p] = *(const float4*)&A[(size_t)(i0 + r) * DDIM + k0 + sc4 * 4];
                pb[p] = *(const float4*)&B[(size_t)(j0 + r) * DDIM + k0 + sc4 * 4];
            }
        }
#pragma unroll
        for (int ks = 0; ks < 2; ++ks) {
            const int kb = ks * 4 + lq;
            s8v afh[2], afl[2], bfh[2], bfl[2];
#pragma unroll
            for (int g = 0; g < 2; ++g) {
                int ra = mh + g * 16 + lm;
                int rb = nh + g * 16 + lm;
                int aa = ra * 64 + ((kb ^ (ra & 7)) << 3);
                int ab = rb * 64 + ((kb ^ (rb & 7)) << 3);
                afh[g] = *(const s8v*)&Ah[aa];
                afl[g] = *(const s8v*)&Al[aa];
                bfh[g] = *(const s8v*)&Bh[ab];
                bfl[g] = *(const s8v*)&Bl[ab];
            }
#pragma unroll
            for (int mi = 0; mi < 2; ++mi)
#pragma unroll
                for (int ni = 0; ni < 2; ++ni) {
                    acc[mi][ni] = __builtin_amdgcn_mfma_f32_16x16x32_bf16(
                        afh[mi], bfh[ni], acc[mi][ni], 0, 0, 0);
                    acc[mi][ni] = __builtin_amdgcn_mfma_f32_16x16x32_bf16(
                        afh[mi], bfl[ni], acc[mi][ni], 0, 0, 0);
                    acc[mi][ni] = __builtin_amdgcn_mfma_f32_16x16x32_bf16(
                        afl[mi], bfh[ni], acc[mi][ni], 0, 0, 0);
                }
        }
    }

    const float CLAMP = 8192.0f;   // 2^13: scaled 8-term den < 2^104
    const float SCw   = 1.220703125e-4f;   // c = 2^-13 (pre-scale eq)
#pragma unroll
    for (int mi = 0; mi < 2; ++mi) {
#pragma unroll
        for (int ni = 0; ni < 2; ++ni) {
#pragma unroll
            for (int p = 0; p < 4; ++p) {
                int row = i0 + mh + mi * 16 + lq * 4 + p;
                int col = j0 + nh + ni * 16 + lm;
                float val = acc[mi][ni][p] + (biasRow ? bias[row] : bias[col]);
                if (blockIdx.z == 0) {
                    eq[(size_t)row * 512 + col] =
                        fminf(__builtin_amdgcn_exp2f(val * CS), CLAMP) * SCw;
                } else if (blockIdx.z == 1) {
                    ekT[(size_t)row * 1024 + col] =
                        fminf(__builtin_amdgcn_exp2f(val * CS), CLAMP);
                } else {
                    ushort2 h2 = f2bf2(val, val);
                    vph[(size_t)row * 1024 + col] = h2.x;
                    ushort2 l2 = f2bf2(val - bf2f(h2.x), 0.f);
                    vpl[(size_t)row * 1024 + col] = l2.x;
                }
            }
        }
    }
}

// ---------------- K2: score+softmax fused (full-d, barrier-free) -------------
// P[n][m] = mask ? exp2(C2 * sum_{d=0..511} Ww[d]/(1+eq*ek)) : 0 -> bf16 h/l
// rsum[n] += row-partial (shfl-reduced, 1 atomic per wave per n).
// Block 4n x 128m x 512d; wave w owns row n0+w; lane owns 2 m. Barrier-free
// streaming engine (R25): per-lane global k-stream, named-reg dbuf a0..7/b0..7.
// Grid (8,256) = 2048 blocks = 8/CU. LDS: es 8KB + wws 2KB = 10KB.
#define SMCH 128

#define TREE8(K0,K1,K2,K3,K4,K5,K6,K7,DCQ)                                     \
    {                                                                          \
        float4 wgA = *(const float4*)&wws[(DCQ)];                              \
        float4 wgB = *(const float4*)&wws[(DCQ) + 4];                          \
        float4 egA = *(const float4*)&esw[(DCQ)];                              \
        float4 egB = *(const float4*)&esw[(DCQ) + 4];                          \
        v2f A0 = __builtin_elementwise_fma(K0, (v2f){egA.x, egA.x}, cc2);      \
        v2f A1 = __builtin_elementwise_fma(K1, (v2f){egA.y, egA.y}, cc2);      \
        v2f A2 = __builtin_elementwise_fma(K2, (v2f){egA.z, egA.z}, cc2);      \
        v2f A3 = __builtin_elementwise_fma(K3, (v2f){egA.w, egA.w}, cc2);      \
        v2f A4 = __builtin_elementwise_fma(K4, (v2f){egB.x, egB.x}, cc2);      \
        v2f A5 = __builtin_elementwise_fma(K5, (v2f){egB.y, egB.y}, cc2);      \
        v2f A6 = __builtin_elementwise_fma(K6, (v2f){egB.z, egB.z}, cc2);      \
        v2f A7 = __builtin_elementwise_fma(K7, (v2f){egB.w, egB.w}, cc2);      \
        v2f n01 = __builtin_elementwise_fma((v2f){wgA.y, wgA.y}, A0,           \
                                            (v2f){wgA.x, wgA.x} * A1);         \
        v2f d01 = A0 * A1;                                                     \
        v2f n23 = __builtin_elementwise_fma((v2f){wgA.w, wgA.w}, A2,           \
                                            (v2f){wgA.z, wgA.z} * A3);         \
        v2f d23 = A2 * A3;                                                     \
        v2f n45 = __builtin_elementwise_fma((v2f){wgB.y, wgB.y}, A4,           \
                                            (v2f){wgB.x, wgB.x} * A5);         \
        v2f d45 = A4 * A5;                                                     \
        v2f n67 = __builtin_elementwise_fma((v2f){wgB.w, wgB.w}, A6,           \
                                            (v2f){wgB.z, wgB.z} * A7);         \
        v2f d67 = A6 * A7;                                                     \
        v2f nA = __builtin_elementwise_fma(n01, d23, n23 * d01);               \
        v2f dA = d01 * d23;                                                    \
        v2f nB = __builtin_elementwise_fma(n45, d67, n67 * d45);               \
        v2f dB = d45 * d67;                                                    \
        v2f num = __builtin_elementwise_fma(nA, dB, nB * dA);                  \
        v2f den = dA * dB;                                                     \
        v2f r = {__builtin_amdgcn_rcpf(den.x),                                 \
                 __builtin_amdgcn_rcpf(den.y)};                                \
        acc = __builtin_elementwise_fma(num, r, acc);                          \
    }

__global__ __launch_bounds__(256) void score_kernel(const float* __restrict__ eq,
                                                    const float* __restrict__ ekT,
                                                    const float* __restrict__ Ww,
                                                    const int* __restrict__ mask,
                                                    ushort* __restrict__ Ph,
                                                    ushort* __restrict__ Pl,
                                                    float* __restrict__ rsum)
{
    __shared__ __align__(16) float es[4 * 512];      // 8 KB (pre-scaled eq)
    __shared__ __align__(16) float wws[512];         // 2 KB (scaled)
    const int t    = threadIdx.x;
    const int lane = t & 63;
    const int w    = t >> 6;
    const int m0   = blockIdx.x * SMCH;
    const int n0   = blockIdx.y * 4;

    const float SC = 1.220703125e-4f;        // c = 2^-13

    // stage es: 4 rows x 512 floats = 512 float4-slots; 256 threads x 2
#pragma unroll
    for (int p = 0; p < 2; ++p) {
        int idx = t + p * 256;
        int nl = idx >> 7, c4 = idx & 127;
        *(float4*)&es[nl * 512 + c4 * 4] =
            *(const float4*)&eq[(size_t)(n0 + nl) * DDIM + c4 * 4];
    }
    wws[t]       = Ww[t] * SC;
    wws[t + 256] = Ww[t + 256] * SC;

    // per-lane global k stream: lane owns columns m0+lane*2, m0+lane*2+1
    const float* gk = ekT + m0 + lane * 2;

    // prologue: rows 0..7 -> a
    v2f a0 = *(const v2f*)(gk + (size_t)0 * MDIM);
    v2f a1 = *(const v2f*)(gk + (size_t)1 * MDIM);
    v2f a2 = *(const v2f*)(gk + (size_t)2 * MDIM);
    v2f a3 = *(const v2f*)(gk + (size_t)3 * MDIM);
    v2f a4 = *(const v2f*)(gk + (size_t)4 * MDIM);
    v2f a5 = *(const v2f*)(gk + (size_t)5 * MDIM);
    v2f a6 = *(const v2f*)(gk + (size_t)6 * MDIM);
    v2f a7 = *(const v2f*)(gk + (size_t)7 * MDIM);

    __syncthreads();   // es/wws visible (only barrier in the kernel)

    const float* esw = &es[w * 512];   // wave's n-row (wave-uniform)
    v2f acc = {0.f, 0.f};
    const v2f cc2 = {1.220703125e-4f, 1.220703125e-4f};   // {c, c}

    for (int dc = 0; dc < 512; dc += 16) {
        const float* g8 = gk + (size_t)(dc + 8) * MDIM;
        v2f b0 = *(const v2f*)(g8 + (size_t)0 * MDIM);
        v2f b1 = *(const v2f*)(g8 + (size_t)1 * MDIM);
        v2f b2 = *(const v2f*)(g8 + (size_t)2 * MDIM);
        v2f b3 = *(const v2f*)(g8 + (size_t)3 * MDIM);
        v2f b4 = *(const v2f*)(g8 + (size_t)4 * MDIM);
        v2f b5 = *(const v2f*)(g8 + (size_t)5 * MDIM);
        v2f b6 = *(const v2f*)(g8 + (size_t)6 * MDIM);
        v2f b7 = *(const v2f*)(g8 + (size_t)7 * MDIM);

        TREE8(a0, a1, a2, a3, a4, a5, a6, a7, dc)

        if (dc + 16 < 512) {
            const float* g16 = gk + (size_t)(dc + 16) * MDIM;
            a0 = *(const v2f*)(g16 + (size_t)0 * MDIM);
            a1 = *(const v2f*)(g16 + (size_t)1 * MDIM);
            a2 = *(const v2f*)(g16 + (size_t)2 * MDIM);
            a3 = *(const v2f*)(g16 + (size_t)3 * MDIM);
            a4 = *(const v2f*)(g16 + (size_t)4 * MDIM);
            a5 = *(const v2f*)(g16 + (size_t)5 * MDIM);
            a6 = *(const v2f*)(g16 + (size_t)6 * MDIM);
            a7 = *(const v2f*)(g16 + (size_t)7 * MDIM);
        }

        TREE8(b0, b1, b2, b3, b4, b5, b6, b7, dc + 8)
    }

    // fused softmax epilogue: mask + exp2 + bf16 h/l + row-partial sum
    const float C2 = -2.8853900817779268f;   // -2*log2(e)
    const int n = n0 + w;
    const int m = m0 + lane * 2;
    int2 mk = *(const int2*)&mask[(size_t)n * MDIM + m];
    float p0 = mk.x ? __builtin_amdgcn_exp2f(acc.x * C2) : 0.f;
    float p1 = mk.y ? __builtin_amdgcn_exp2f(acc.y * C2) : 0.f;

    ushort2 h, l;
    hl2(p0, p1, h, l);
    *(ushort2*)&Ph[(size_t)n * MDIM + m] = h;
    *(ushort2*)&Pl[(size_t)n * MDIM + m] = l;

    float rs = p0 + p1;
#pragma unroll
    for (int off = 32; off; off >>= 1) rs += __shfl_xor(rs, off);
    if (lane == 0) atomicAdd(&rsum[n], rs);
}

// ---------------- K3: context MFMA (m-split x4 + LDS reduce) -----------------
// out[n][d] = (sum_m P[n][m]*vpT[d][m]) * rcp(rsum[n])
// grid (32,64) = 2048 blocks = 8/CU. Wave w sums m in [w*256,(w+1)*256);
// partials LDS-reduced by wave 0.
__global__ __launch_bounds__(256) void ctx_gemm(const ushort* __restrict__ Ph,
                                                const ushort* __restrict__ Pl,
                                                const ushort* __restrict__ vph,
                                                const ushort* __restrict__ vpl,
                                                const float* __restrict__ rsum,
                                                float* __restrict__ out)
{
    __shared__ __align__(16) float red[3 * 64 * 4];   // 3 KB
    const int t    = threadIdx.x;
    const int lane = t & 63;
    const int w    = t >> 6;
    const int lm   = lane & 15;
    const int lq   = lane >> 4;
    const int d0   = blockIdx.x * 16;
    const int n0   = blockIdx.y * 16;
    const int mb   = w * 256;

    const ushort* pAh = Ph  + (size_t)(n0 + lm) * MDIM + mb + lq * 8;
    const ushort* pAl = Pl  + (size_t)(n0 + lm) * MDIM + mb + lq * 8;
    const ushort* pBh = vph + (size_t)(d0 + lm) * MDIM + mb + lq * 8;
    const ushort* pBl = vpl + (size_t)(d0 + lm) * MDIM + mb + lq * 8;

    f4v acc = {0.f, 0.f, 0.f, 0.f};
#pragma unroll 4
    for (int m0 = 0; m0 < 256; m0 += 32) {
        s8v ah = *(const s8v*)(pAh + m0);
        s8v al = *(const s8v*)(pAl + m0);
        s8v bh = *(const s8v*)(pBh + m0);
        s8v bl = *(const s8v*)(pBl + m0);
        acc = __builtin_amdgcn_mfma_f32_16x16x32_bf16(ah, bh, acc, 0, 0, 0);
        acc = __builtin_amdgcn_mfma_f32_16x16x32_bf16(ah, bl, acc, 0, 0, 0);
        acc = __builtin_amdgcn_mfma_f32_16x16x32_bf16(al, bh, acc, 0, 0, 0);
    }

    if (w > 0) *(f4v*)&red[((w - 1) * 64 + lane) * 4] = acc;
    __syncthreads();
    if (w == 0) {
#pragma unroll
        for (int i = 0; i < 3; ++i)
            acc += *(const f4v*)&red[(i * 64 + lane) * 4];
#pragma unroll
        for (int p = 0; p < 4; ++p) {
            int nrow = n0 + lq * 4 + p;
            float inv = __builtin_amdgcn_rcpf(rsum[nrow]);
            out[(size_t)nrow * DDIM + d0 + lm] = acc[p] * inv;
        }
    }
}

extern "C" void kernel_launch(void* const* d_in, const int* in_sizes, int n_in,
                              void* d_out, int out_size, void* d_ws, size_t ws_size,
                              hipStream_t stream)
{
    const float* q    = (const float*)d_in[0];
    const float* k    = (const float*)d_in[1];
    const float* v    = (const float*)d_in[2];
    const int*   mask = (const int*)d_in[3];
    const float* Wq   = (const float*)d_in[4];
    const float* bq   = (const float*)d_in[5];
    const float* Wk   = (const float*)d_in[6];
    const float* bk   = (const float*)d_in[7];
    const float* Wv   = (const float*)d_in[8];
    const float* bv   = (const float*)d_in[9];
    const float* Ww   = (const float*)d_in[10];
    // d_in[11] (bw) cancels under softmax.

    float* ws    = (float*)d_ws;
    float* eq    = ws;                       // 512K floats [1024 n][512 d]
    float* ekT   = ws + 524288;              // 512K [512 d][1024 m]
    ushort* vph  = (ushort*)(ws + 1048576);  // 1M ushorts [512 d][1024 m]
    ushort* vpl  = (ushort*)(ws + 1310720);  // 1M ushorts
    ushort* Ph   = (ushort*)(ws + 1572864);  // 1M ushorts [1024 n][1024 m]
    ushort* Pl   = (ushort*)(ws + 2097152);  // 1M ushorts
    float* rsum  = ws + 2621440;             // 1K floats
    float* out   = (float*)d_out;

    const float CS = 2.8853900817779268f;    // 2*log2(e)

    proj_gemm<<<dim3(16, 8, 3), dim3(256), 0, stream>>>(q, k, v, Wq, bq, Wk, bk,
                                                        Wv, bv, eq, ekT,
                                                        vph, vpl, rsum, CS);
    score_kernel<<<dim3(8, 256), dim3(256), 0, stream>>>(eq, ekT, Ww, mask,
                                                         Ph, Pl, rsum);
    ctx_gemm<<<dim3(32, 64), dim3(256), 0, stream>>>(Ph, Pl, vph, vpl, rsum, out);
}

// Round 8
// 176.073 us; speedup vs baseline: 1.3762x; 1.3762x over previous
//
#include <hip/hip_runtime.h>
#include <hip/hip_bf16.h>
#include <float.h>

// N=1024, M=1024, D=512, fp32 in/out.
// tanh(q+k) = 1 - 2/(1+exp2(CS*(q+k))), CS=2*log2(e), exp2 factorized:
// eq[n][d]=min(exp2(CS*qp),2^13)*c (c=2^-13 pre-scaled in proj),
// ekT[d][m]=min(exp2(CS*kp),2^13)^T.
// s[n,m] = -2*sum_d Ww[d]/(1+eq*ek) (row-const dropped; softmax shift-inv).
// R19: 8-term rational merge (1 rcp per 8 d via 3-level tree, c^8 scaling).
// R20-R25: score VALU floor ~33us; barrier-free reg-prefetch engine best.
// R26: fused combine into score (WRITE 33->4.4MB, residue 121->107us) BUT
// 1n-per-wave tiling destroyed k-reuse (load:eval 8:1, L2 traffic 2GB) ->
// score 135us, VALUBusy 39%.
// R27: fused epilogue KEPT, k-reuse RESTORED: block 4n x 512m x 512d; the 4
// waves split M (wave w owns 128 m-cols), every wave computes all 4 n from
// shared es. Per wave: 512 k-rows serve 4n x 2m -> load:eval 2:1, L2 traffic
// back to 512MB. Grid (2,256)=512 blocks=2/CU; per-thread work 4x R26.
// ws: eq 2MB | ekT 2MB | vph/vpl 2MB | Ph/Pl 4MB | rsum 4KB.

#define NROWS 1024
#define DDIM  512
#define MDIM  1024

typedef __attribute__((ext_vector_type(8))) short s8v;    // 8 bf16, 4 VGPR
typedef __attribute__((ext_vector_type(4))) float f4v;
typedef __attribute__((ext_vector_type(2))) float v2f;

__device__ __forceinline__ float bf2f(ushort h) {
    return __uint_as_float(((unsigned)h) << 16);
}
__device__ __forceinline__ ushort2 f2bf2(float a, float b) {   // packed cvt
    __hip_bfloat162 t = __float22bfloat162_rn(float2{a, b});
    union { __hip_bfloat162 v; ushort2 u; } c; c.v = t;
    return c.u;
}
__device__ __forceinline__ void hl2(float a, float b, ushort2& h, ushort2& l) {
    h = f2bf2(a, b);
    l = f2bf2(a - bf2f(h.x), b - bf2f(h.y));
}

// ---------------- K1: fused projection GEMMs (MFMA bf16 hi/lo, A^T-B) --------
// z=0: eq[n][d]:  A=q,  B=Wq, bias col, exp2+clamp, *c. Block (0,0,0) zeroes rsum.
// z=1: ekT[d][m]: A=Wk, B=kk, bias row, exp2+clamp.
// z=2: vpT[d][m]: A=Wv, B=v,  bias row, bf16 h/l out.
__global__ __launch_bounds__(256) void proj_gemm(
    const float* __restrict__ q, const float* __restrict__ kk_,
    const float* __restrict__ v,
    const float* __restrict__ Wq, const float* __restrict__ bq,
    const float* __restrict__ Wk, const float* __restrict__ bk,
    const float* __restrict__ Wv, const float* __restrict__ bv,
    float* __restrict__ eq, float* __restrict__ ekT,
    ushort* __restrict__ vph, ushort* __restrict__ vpl,
    float* __restrict__ rsum, float CS)
{
    __shared__ ushort Ah[4096], Al[4096], Bh[4096], Bl[4096];   // 32 KB

    const float* A; const float* B; const float* bias;
    int biasRow;
    if (blockIdx.z == 0)      { A = q;   B = Wq;  bias = bq; biasRow = 0; }
    else if (blockIdx.z == 1) { A = Wk;  B = kk_; bias = bk; biasRow = 1; }
    else                      { A = Wv;  B = v;   bias = bv; biasRow = 1; }

    const int bi = (blockIdx.z == 0) ? blockIdx.x : blockIdx.y;
    const int bj = (blockIdx.z == 0) ? blockIdx.y : blockIdx.x;

    const int t    = threadIdx.x;
    const int lane = t & 63;
    const int w    = t >> 6;
    const int lm   = lane & 15;
    const int lq   = lane >> 4;
    const int i0   = bi * 64;
    const int j0   = bj * 64;
    const int mh   = (w >> 1) * 32;
    const int nh   = (w & 1) * 32;

    // zero rsum (1024 floats) for score's atomics
    if (blockIdx.z == 0 && blockIdx.x == 0 && blockIdx.y == 0) {
        float4 zz = {0.f, 0.f, 0.f, 0.f};
        *(float4*)&rsum[t * 4] = zz;
    }

    f4v acc[2][2] = {{{0.f,0.f,0.f,0.f},{0.f,0.f,0.f,0.f}},
                     {{0.f,0.f,0.f,0.f},{0.f,0.f,0.f,0.f}}};
    float4 pa[4], pb[4];

    const int sr = t >> 4, sc4 = t & 15;
#pragma unroll
    for (int p = 0; p < 4; ++p) {
        int r = sr + p * 16;
        pa[p] = *(const float4*)&A[(size_t)(i0 + r) * DDIM + sc4 * 4];
        pb[p] = *(const float4*)&B[(size_t)(j0 + r) * DDIM + sc4 * 4];
    }

    for (int kc = 0; kc < 8; ++kc) {
        __syncthreads();
#pragma unroll
        for (int p = 0; p < 4; ++p) {
            int r = sr + p * 16;
            int ad = r * 64 + (((sc4 >> 1) ^ (r & 7)) << 3) + (sc4 & 1) * 4;
            ushort2 h01, l01, h23, l23;
            hl2(pa[p].x, pa[p].y, h01, l01);
            hl2(pa[p].z, pa[p].w, h23, l23);
            ushort4 ha = {h01.x, h01.y, h23.x, h23.y};
            ushort4 la = {l01.x, l01.y, l23.x, l23.y};
            *(ushort4*)&Ah[ad] = ha;
            *(ushort4*)&Al[ad] = la;
            hl2(pb[p].x, pb[p].y, h01, l01);
            hl2(pb[p].z, pb[p].w, h23, l23);
            ushort4 hb = {h01.x, h01.y, h23.x, h23.y};
            ushort4 lb = {l01.x, l01.y, l23.x, l23.y};
            *(ushort4*)&Bh[ad] = hb;
            *(ushort4*)&Bl[ad] = lb;
        }
        __syncthreads();
        if (kc < 7) {
            const int k0 = (kc + 1) * 64;
#pragma unroll
            for (int p = 0; p < 4; ++p) {
                int r = sr + p * 16;
                pa[p] = *(const float4*)&A[(size_t)(i0 + r) * DDIM + k0 + sc4 * 4];
                pb[p] = *(const float4*)&B[(size_t)(j0 + r) * DDIM + k0 + sc4 * 4];
            }
        }
#pragma unroll
        for (int ks = 0; ks < 2; ++ks) {
            const int kb = ks * 4 + lq;
            s8v afh[2], afl[2], bfh[2], bfl[2];
#pragma unroll
            for (int g = 0; g < 2; ++g) {
                int ra = mh + g * 16 + lm;
                int rb = nh + g * 16 + lm;
                int aa = ra * 64 + ((kb ^ (ra & 7)) << 3);
                int ab = rb * 64 + ((kb ^ (rb & 7)) << 3);
                afh[g] = *(const s8v*)&Ah[aa];
                afl[g] = *(const s8v*)&Al[aa];
                bfh[g] = *(const s8v*)&Bh[ab];
                bfl[g] = *(const s8v*)&Bl[ab];
            }
#pragma unroll
            for (int mi = 0; mi < 2; ++mi)
#pragma unroll
                for (int ni = 0; ni < 2; ++ni) {
                    acc[mi][ni] = __builtin_amdgcn_mfma_f32_16x16x32_bf16(
                        afh[mi], bfh[ni], acc[mi][ni], 0, 0, 0);
                    acc[mi][ni] = __builtin_amdgcn_mfma_f32_16x16x32_bf16(
                        afh[mi], bfl[ni], acc[mi][ni], 0, 0, 0);
                    acc[mi][ni] = __builtin_amdgcn_mfma_f32_16x16x32_bf16(
                        afl[mi], bfh[ni], acc[mi][ni], 0, 0, 0);
                }
        }
    }

    const float CLAMP = 8192.0f;   // 2^13: scaled 8-term den < 2^104
    const float SCw   = 1.220703125e-4f;   // c = 2^-13 (pre-scale eq)
#pragma unroll
    for (int mi = 0; mi < 2; ++mi) {
#pragma unroll
        for (int ni = 0; ni < 2; ++ni) {
#pragma unroll
            for (int p = 0; p < 4; ++p) {
                int row = i0 + mh + mi * 16 + lq * 4 + p;
                int col = j0 + nh + ni * 16 + lm;
                float val = acc[mi][ni][p] + (biasRow ? bias[row] : bias[col]);
                if (blockIdx.z == 0) {
                    eq[(size_t)row * 512 + col] =
                        fminf(__builtin_amdgcn_exp2f(val * CS), CLAMP) * SCw;
                } else if (blockIdx.z == 1) {
                    ekT[(size_t)row * 1024 + col] =
                        fminf(__builtin_amdgcn_exp2f(val * CS), CLAMP);
                } else {
                    ushort2 h2 = f2bf2(val, val);
                    vph[(size_t)row * 1024 + col] = h2.x;
                    ushort2 l2 = f2bf2(val - bf2f(h2.x), 0.f);
                    vpl[(size_t)row * 1024 + col] = l2.x;
                }
            }
        }
    }
}

// ---------------- K2: score+softmax fused (full-d, 4n-reuse, barrier-free) ---
// P[n][m] = mask ? exp2(C2 * sum_{d=0..511} Ww[d]/(1+eq*ek)) : 0 -> bf16 h/l
// rsum[n] += wave partial (shfl-reduced, 1 atomic per wave per n).
// Block 4n x 512m x 512d: waves split M (wave w owns 128 m-cols, lane 2m);
// EVERY wave computes all 4 n from the shared es -> each loaded k-row serves
// 4n x 2m (load:eval 2:1, R25's ratio). Barrier-free k-stream, named-reg dbuf.
// Grid (2,256) = 512 blocks = 2/CU. LDS: es 8KB + wws 2KB = 10KB.

#define TREE8(K0,K1,K2,K3,K4,K5,K6,K7,DCQ)                                     \
    {                                                                          \
        float4 wgA = *(const float4*)&wws[(DCQ)];                              \
        float4 wgB = *(const float4*)&wws[(DCQ) + 4];                          \
        _Pragma("unroll")                                                      \
        for (int nn = 0; nn < 4; ++nn) {                                       \
            float4 egA = *(const float4*)&es[nn * 512 + (DCQ)];                \
            float4 egB = *(const float4*)&es[nn * 512 + (DCQ) + 4];            \
            v2f A0 = __builtin_elementwise_fma(K0, (v2f){egA.x, egA.x}, cc2);  \
            v2f A1 = __builtin_elementwise_fma(K1, (v2f){egA.y, egA.y}, cc2);  \
            v2f A2 = __builtin_elementwise_fma(K2, (v2f){egA.z, egA.z}, cc2);  \
            v2f A3 = __builtin_elementwise_fma(K3, (v2f){egA.w, egA.w}, cc2);  \
            v2f A4 = __builtin_elementwise_fma(K4, (v2f){egB.x, egB.x}, cc2);  \
            v2f A5 = __builtin_elementwise_fma(K5, (v2f){egB.y, egB.y}, cc2);  \
            v2f A6 = __builtin_elementwise_fma(K6, (v2f){egB.z, egB.z}, cc2);  \
            v2f A7 = __builtin_elementwise_fma(K7, (v2f){egB.w, egB.w}, cc2);  \
            v2f n01 = __builtin_elementwise_fma((v2f){wgA.y, wgA.y}, A0,       \
                                                (v2f){wgA.x, wgA.x} * A1);     \
            v2f d01 = A0 * A1;                                                 \
            v2f n23 = __builtin_elementwise_fma((v2f){wgA.w, wgA.w}, A2,       \
                                                (v2f){wgA.z, wgA.z} * A3);     \
            v2f d23 = A2 * A3;                                                 \
            v2f n45 = __builtin_elementwise_fma((v2f){wgB.y, wgB.y}, A4,       \
                                                (v2f){wgB.x, wgB.x} * A5);     \
            v2f d45 = A4 * A5;                                                 \
            v2f n67 = __builtin_elementwise_fma((v2f){wgB.w, wgB.w}, A6,       \
                                                (v2f){wgB.z, wgB.z} * A7);     \
            v2f d67 = A6 * A7;                                                 \
            v2f nA = __builtin_elementwise_fma(n01, d23, n23 * d01);           \
            v2f dA = d01 * d23;                                                \
            v2f nB = __builtin_elementwise_fma(n45, d67, n67 * d45);           \
            v2f dB = d45 * d67;                                                \
            v2f num = __builtin_elementwise_fma(nA, dB, nB * dA);              \
            v2f den = dA * dB;                                                 \
            v2f r = {__builtin_amdgcn_rcpf(den.x),                             \
                     __builtin_amdgcn_rcpf(den.y)};                            \
            acc[nn] = __builtin_elementwise_fma(num, r, acc[nn]);              \
        }                                                                      \
    }

__global__ __launch_bounds__(256) void score_kernel(const float* __restrict__ eq,
                                                    const float* __restrict__ ekT,
                                                    const float* __restrict__ Ww,
                                                    const int* __restrict__ mask,
                                                    ushort* __restrict__ Ph,
                                                    ushort* __restrict__ Pl,
                                                    float* __restrict__ rsum)
{
    __shared__ __align__(16) float es[4 * 512];      // 8 KB (pre-scaled eq)
    __shared__ __align__(16) float wws[512];         // 2 KB (scaled)
    const int t    = threadIdx.x;
    const int lane = t & 63;
    const int w    = t >> 6;
    const int mw   = blockIdx.x * 512 + w * 128;     // wave's m-base
    const int n0   = blockIdx.y * 4;

    const float SC = 1.220703125e-4f;        // c = 2^-13

    // stage es: 4 rows x 512 floats = 512 float4-slots; 256 threads x 2
#pragma unroll
    for (int p = 0; p < 2; ++p) {
        int idx = t + p * 256;
        int nl = idx >> 7, c4 = idx & 127;
        *(float4*)&es[nl * 512 + c4 * 4] =
            *(const float4*)&eq[(size_t)(n0 + nl) * DDIM + c4 * 4];
    }
    wws[t]       = Ww[t] * SC;
    wws[t + 256] = Ww[t + 256] * SC;

    // per-lane global k stream: lane owns columns mw+lane*2, mw+lane*2+1
    const float* gk = ekT + mw + lane * 2;

    // prologue: rows 0..7 -> a
    v2f a0 = *(const v2f*)(gk + (size_t)0 * MDIM);
    v2f a1 = *(const v2f*)(gk + (size_t)1 * MDIM);
    v2f a2 = *(const v2f*)(gk + (size_t)2 * MDIM);
    v2f a3 = *(const v2f*)(gk + (size_t)3 * MDIM);
    v2f a4 = *(const v2f*)(gk + (size_t)4 * MDIM);
    v2f a5 = *(const v2f*)(gk + (size_t)5 * MDIM);
    v2f a6 = *(const v2f*)(gk + (size_t)6 * MDIM);
    v2f a7 = *(const v2f*)(gk + (size_t)7 * MDIM);

    __syncthreads();   // es/wws visible (only barrier in the kernel)

    v2f acc[4] = {};
    const v2f cc2 = {1.220703125e-4f, 1.220703125e-4f};   // {c, c}

    for (int dc = 0; dc < 512; dc += 16) {
        const float* g8 = gk + (size_t)(dc + 8) * MDIM;
        v2f b0 = *(const v2f*)(g8 + (size_t)0 * MDIM);
        v2f b1 = *(const v2f*)(g8 + (size_t)1 * MDIM);
        v2f b2 = *(const v2f*)(g8 + (size_t)2 * MDIM);
        v2f b3 = *(const v2f*)(g8 + (size_t)3 * MDIM);
        v2f b4 = *(const v2f*)(g8 + (size_t)4 * MDIM);
        v2f b5 = *(const v2f*)(g8 + (size_t)5 * MDIM);
        v2f b6 = *(const v2f*)(g8 + (size_t)6 * MDIM);
        v2f b7 = *(const v2f*)(g8 + (size_t)7 * MDIM);

        TREE8(a0, a1, a2, a3, a4, a5, a6, a7, dc)

        if (dc + 16 < 512) {
            const float* g16 = gk + (size_t)(dc + 16) * MDIM;
            a0 = *(const v2f*)(g16 + (size_t)0 * MDIM);
            a1 = *(const v2f*)(g16 + (size_t)1 * MDIM);
            a2 = *(const v2f*)(g16 + (size_t)2 * MDIM);
            a3 = *(const v2f*)(g16 + (size_t)3 * MDIM);
            a4 = *(const v2f*)(g16 + (size_t)4 * MDIM);
            a5 = *(const v2f*)(g16 + (size_t)5 * MDIM);
            a6 = *(const v2f*)(g16 + (size_t)6 * MDIM);
            a7 = *(const v2f*)(g16 + (size_t)7 * MDIM);
        }

        TREE8(b0, b1, b2, b3, b4, b5, b6, b7, dc + 8)
    }

    // fused softmax epilogue: mask + exp2 + bf16 h/l + row partials
    const float C2 = -2.8853900817779268f;   // -2*log2(e)
    const int m = mw + lane * 2;
    float rs[4];
#pragma unroll
    for (int nn = 0; nn < 4; ++nn) {
        int n = n0 + nn;
        int2 mk = *(const int2*)&mask[(size_t)n * MDIM + m];
        float p0 = mk.x ? __builtin_amdgcn_exp2f(acc[nn].x * C2) : 0.f;
        float p1 = mk.y ? __builtin_amdgcn_exp2f(acc[nn].y * C2) : 0.f;
        ushort2 h, l;
        hl2(p0, p1, h, l);
        *(ushort2*)&Ph[(size_t)n * MDIM + m] = h;
        *(ushort2*)&Pl[(size_t)n * MDIM + m] = l;
        rs[nn] = p0 + p1;
    }
#pragma unroll
    for (int off = 32; off; off >>= 1) {
        rs[0] += __shfl_xor(rs[0], off);
        rs[1] += __shfl_xor(rs[1], off);
        rs[2] += __shfl_xor(rs[2], off);
        rs[3] += __shfl_xor(rs[3], off);
    }
    if (lane == 0) {
#pragma unroll
        for (int nn = 0; nn < 4; ++nn)
            atomicAdd(&rsum[n0 + nn], rs[nn]);
    }
}

// ---------------- K3: context MFMA (m-split x4 + LDS reduce) -----------------
// out[n][d] = (sum_m P[n][m]*vpT[d][m]) * rcp(rsum[n])
// grid (32,64) = 2048 blocks = 8/CU. Wave w sums m in [w*256,(w+1)*256);
// partials LDS-reduced by wave 0.
__global__ __launch_bounds__(256) void ctx_gemm(const ushort* __restrict__ Ph,
                                                const ushort* __restrict__ Pl,
                                                const ushort* __restrict__ vph,
                                                const ushort* __restrict__ vpl,
                                                const float* __restrict__ rsum,
                                                float* __restrict__ out)
{
    __shared__ __align__(16) float red[3 * 64 * 4];   // 3 KB
    const int t    = threadIdx.x;
    const int lane = t & 63;
    const int w    = t >> 6;
    const int lm   = lane & 15;
    const int lq   = lane >> 4;
    const int d0   = blockIdx.x * 16;
    const int n0   = blockIdx.y * 16;
    const int mb   = w * 256;

    const ushort* pAh = Ph  + (size_t)(n0 + lm) * MDIM + mb + lq * 8;
    const ushort* pAl = Pl  + (size_t)(n0 + lm) * MDIM + mb + lq * 8;
    const ushort* pBh = vph + (size_t)(d0 + lm) * MDIM + mb + lq * 8;
    const ushort* pBl = vpl + (size_t)(d0 + lm) * MDIM + mb + lq * 8;

    f4v acc = {0.f, 0.f, 0.f, 0.f};
#pragma unroll 4
    for (int m0 = 0; m0 < 256; m0 += 32) {
        s8v ah = *(const s8v*)(pAh + m0);
        s8v al = *(const s8v*)(pAl + m0);
        s8v bh = *(const s8v*)(pBh + m0);
        s8v bl = *(const s8v*)(pBl + m0);
        acc = __builtin_amdgcn_mfma_f32_16x16x32_bf16(ah, bh, acc, 0, 0, 0);
        acc = __builtin_amdgcn_mfma_f32_16x16x32_bf16(ah, bl, acc, 0, 0, 0);
        acc = __builtin_amdgcn_mfma_f32_16x16x32_bf16(al, bh, acc, 0, 0, 0);
    }

    if (w > 0) *(f4v*)&red[((w - 1) * 64 + lane) * 4] = acc;
    __syncthreads();
    if (w == 0) {
#pragma unroll
        for (int i = 0; i < 3; ++i)
            acc += *(const f4v*)&red[(i * 64 + lane) * 4];
#pragma unroll
        for (int p = 0; p < 4; ++p) {
            int nrow = n0 + lq * 4 + p;
            float inv = __builtin_amdgcn_rcpf(rsum[nrow]);
            out[(size_t)nrow * DDIM + d0 + lm] = acc[p] * inv;
        }
    }
}

extern "C" void kernel_launch(void* const* d_in, const int* in_sizes, int n_in,
                              void* d_out, int out_size, void* d_ws, size_t ws_size,
                              hipStream_t stream)
{
    const float* q    = (const float*)d_in[0];
    const float* k    = (const float*)d_in[1];
    const float* v    = (const float*)d_in[2];
    const int*   mask = (const int*)d_in[3];
    const float* Wq   = (const float*)d_in[4];
    const float* bq   = (const float*)d_in[5];
    const float* Wk   = (const float*)d_in[6];
    const float* bk   = (const float*)d_in[7];
    const float* Wv   = (const float*)d_in[8];
    const float* bv   = (const float*)d_in[9];
    const float* Ww   = (const float*)d_in[10];
    // d_in[11] (bw) cancels under softmax.

    float* ws    = (float*)d_ws;
    float* eq    = ws;                       // 512K floats [1024 n][512 d]
    float* ekT   = ws + 524288;              // 512K [512 d][1024 m]
    ushort* vph  = (ushort*)(ws + 1048576);  // 1M ushorts [512 d][1024 m]
    ushort* vpl  = (ushort*)(ws + 1310720);  // 1M ushorts
    ushort* Ph   = (ushort*)(ws + 1572864);  // 1M ushorts [1024 n][1024 m]
    ushort* Pl   = (ushort*)(ws + 2097152);  // 1M ushorts
    float* rsum  = ws + 2621440;             // 1K floats
    float* out   = (float*)d_out;

    const float CS = 2.8853900817779268f;    // 2*log2(e)

    proj_gemm<<<dim3(16, 8, 3), dim3(256), 0, stream>>>(q, k, v, Wq, bq, Wk, bk,
                                                        Wv, bv, eq, ekT,
                                                        vph, vpl, rsum, CS);
    score_kernel<<<dim3(2, 256), dim3(256), 0, stream>>>(eq, ekT, Ww, mask,
                                                         Ph, Pl, rsum);
    ctx_gemm<<<dim3(32, 64), dim3(256), 0, stream>>>(Ph, Pl, vph, vpl, rsum, out);
}